// Round 5
// baseline (547.898 us; speedup 1.0000x reference)
//
#include <hip/hip_runtime.h>
#include <math.h>

#define B 8
#define C 512
#define K 19
#define HW 16384
#define ROWS (B * K)             // 152
#define L2E 1.44269504088896340736f

// softmax two-phase config
#define NSEG 8
#define SEG (HW / NSEG)          // 2048 elements per segment

// gather config
#define NW 4                     // waves per block
#define CPW 4                    // c-rows per wave -> acc[4][19] = 76 VGPRs
#define CPB (CPW * NW)           // 16 c-rows per block
#define CG (C / CPB)             // 32 c-groups
#define NSC 4                    // grid = 8*32*4 = 1024 = 4 blocks/CU
#define SCHUNK (HW / NSC)        // 4096 s per block
#define TS 256                   // s-tile staged in LDS
#define NT (SCHUNK / TS)         // 16 tiles per block

// Phase A: per-(row,segment) partial softmax stats (single global pass;
// 1216 blocks -> BW-bound, fixes the 152-block latency-bound stats kernel).
__global__ __launch_bounds__(256)
void softmax_partial_kernel(const float* __restrict__ aux, float* __restrict__ partials) {
    int blk = blockIdx.x;                  // 0 .. ROWS*NSEG-1
    int row = blk >> 3;
    int seg = blk & (NSEG - 1);
    const float4* x4 = (const float4*)(aux + (size_t)row * HW + seg * SEG);
    int tid  = threadIdx.x;
    int lane = tid & 63;
    int wave = tid >> 6;
    __shared__ float red[4];

    float4 v0 = x4[tid];
    float4 v1 = x4[tid + 256];
    float m = fmaxf(fmaxf(fmaxf(v0.x, v0.y), fmaxf(v0.z, v0.w)),
                    fmaxf(fmaxf(v1.x, v1.y), fmaxf(v1.z, v1.w)));
    #pragma unroll
    for (int off = 32; off > 0; off >>= 1) m = fmaxf(m, __shfl_xor(m, off, 64));
    if (lane == 0) red[wave] = m;
    __syncthreads();
    m = fmaxf(fmaxf(red[0], red[1]), fmaxf(red[2], red[3]));
    __syncthreads();

    float s = exp2f((v0.x - m) * L2E) + exp2f((v0.y - m) * L2E)
            + exp2f((v0.z - m) * L2E) + exp2f((v0.w - m) * L2E)
            + exp2f((v1.x - m) * L2E) + exp2f((v1.y - m) * L2E)
            + exp2f((v1.z - m) * L2E) + exp2f((v1.w - m) * L2E);
    #pragma unroll
    for (int off = 32; off > 0; off >>= 1) s += __shfl_xor(s, off, 64);
    if (lane == 0) red[wave] = s;
    __syncthreads();
    if (tid == 0) {
        partials[blk * 2]     = m;
        partials[blk * 2 + 1] = red[0] + red[1] + red[2] + red[3];
    }
}

// Phase B: combine NSEG partials per row (online-softmax merge).
__global__ __launch_bounds__(256)
void softmax_combine_kernel(const float* __restrict__ partials, float* __restrict__ stats) {
    int row = threadIdx.x;
    if (row < ROWS) {
        float mj[NSEG], zj[NSEG];
        float m = -INFINITY;
        #pragma unroll
        for (int j = 0; j < NSEG; j++) {
            mj[j] = partials[(row * NSEG + j) * 2];
            zj[j] = partials[(row * NSEG + j) * 2 + 1];
            m = fmaxf(m, mj[j]);
        }
        float Z = 0.f;
        #pragma unroll
        for (int j = 0; j < NSEG; j++) Z += zj[j] * exp2f((mj[j] - m) * L2E);
        stats[row * 2]     = -m * L2E;
        stats[row * 2 + 1] = 1.0f / Z;
    }
}

// Gather: probs staged once per block per tile (double-buffered LDS), feats
// register-prefetched one tile ahead. amdgpu_waves_per_eu(4,4) pins the VGPR
// budget at exactly 128 (R4 showed launch_bounds' 2nd arg lets the allocator
// pick 64 and spill; R3 showed 128 fits). 4 blocks/CU co-resident.
__global__ __launch_bounds__(256)
__attribute__((amdgpu_waves_per_eu(4, 4)))
void gather_kernel(const float* __restrict__ feats, const float* __restrict__ aux,
                   const float* __restrict__ stats, float* __restrict__ out) {
    __shared__ float plds[2][K][TS];          // 38,912 B -> 4 blocks/CU

    int bid  = blockIdx.x;                 // 0 .. 1023
    int sc   = bid & (NSC - 1);
    int cg   = (bid >> 2) & (CG - 1);
    int b    = bid >> 7;
    int tid  = threadIdx.x;
    int lane = tid & 63;
    int wave = tid >> 6;
    int c0   = cg * CPB + wave * CPW;

    const float* Abase = aux   + (size_t)b * K * HW + sc * SCHUNK;
    const float* Fbase = feats + ((size_t)b * C + c0) * HW + sc * SCHUNK;
    const float* S     = stats + (size_t)b * K * 2;

    // softmax stats -> SGPRs
    float negml[K], invz[K];
    #pragma unroll
    for (int k = 0; k < K; k++) {
        negml[k] = __int_as_float(__builtin_amdgcn_readfirstlane(__float_as_int(S[2 * k])));
        invz[k]  = __int_as_float(__builtin_amdgcn_readfirstlane(__float_as_int(S[2 * k + 1])));
    }

    float acc[CPW][K];
    #pragma unroll
    for (int c = 0; c < CPW; c++)
        #pragma unroll
        for (int k = 0; k < K; k++) acc[c][k] = 0.f;

    // prologue: stage probs tile 0 + load feats tile 0
    #pragma unroll
    for (int k = 0; k < K; k++) {
        float a = Abase[k * HW + tid];
        plds[0][k][tid] = exp2f(fmaf(a, L2E, negml[k])) * invz[k];
    }
    float4 f_cur[CPW], f_next[CPW];
    #pragma unroll
    for (int c = 0; c < CPW; c++)
        f_cur[c] = *(const float4*)(Fbase + c * HW + lane * 4);

    for (int t = 0; t < NT; t++) {
        int buf = t & 1;
        __syncthreads();   // plds[buf] staged; prior readers of buf^1 done

        // prefetch feats t+1 first (longest latency distance), then stage
        // probs t+1 into the other LDS buffer.
        if (t + 1 < NT) {
            int s1 = (t + 1) * TS;
            #pragma unroll
            for (int c = 0; c < CPW; c++)
                f_next[c] = *(const float4*)(Fbase + c * HW + s1 + lane * 4);
            float a[K];
            #pragma unroll
            for (int k = 0; k < K; k++) a[k] = Abase[k * HW + s1 + tid];
            #pragma unroll
            for (int k = 0; k < K; k++)
                plds[buf ^ 1][k][tid] = exp2f(fmaf(a[k], L2E, negml[k])) * invz[k];
        }

        // FMA phase on tile t: f_cur (regs) x plds[buf] (ds_read_b128)
        #pragma unroll
        for (int k = 0; k < K; k++) {
            float4 p4 = *(const float4*)(&plds[buf][k][lane * 4]);
            #pragma unroll
            for (int c = 0; c < CPW; c++) {
                acc[c][k] = fmaf(p4.x, f_cur[c].x, acc[c][k]);
                acc[c][k] = fmaf(p4.y, f_cur[c].y, acc[c][k]);
                acc[c][k] = fmaf(p4.z, f_cur[c].z, acc[c][k]);
                acc[c][k] = fmaf(p4.w, f_cur[c].w, acc[c][k]);
            }
        }
        #pragma unroll
        for (int c = 0; c < CPW; c++) f_cur[c] = f_next[c];
    }

    // butterfly reduce over 64 lanes, then one atomic per (c,k) per block
    #pragma unroll
    for (int c = 0; c < CPW; c++)
        #pragma unroll
        for (int k = 0; k < K; k++) {
            float v = acc[c][k];
            #pragma unroll
            for (int off = 32; off > 0; off >>= 1) v += __shfl_xor(v, off, 64);
            if (lane == 0)
                atomicAdd(&out[((size_t)b * C + c0 + c) * K + k], v);
        }
}

extern "C" void kernel_launch(void* const* d_in, const int* in_sizes, int n_in,
                              void* d_out, int out_size, void* d_ws, size_t ws_size,
                              hipStream_t stream) {
    const float* feats = (const float*)d_in[0];   // bb_feats [8,512,128,128]
    const float* aux   = (const float*)d_in[1];   // aux_out  [8,19,128,128]
    float* out      = (float*)d_out;              // [8,512,19,1]
    float* stats    = (float*)d_ws;               // 304 floats
    float* partials = (float*)d_ws + 512;         // 152*8*2 floats

    hipMemsetAsync(d_out, 0, (size_t)out_size * sizeof(float), stream);
    softmax_partial_kernel<<<ROWS * NSEG, 256, 0, stream>>>(aux, partials);
    softmax_combine_kernel<<<1, 256, 0, stream>>>(partials, stats);
    gather_kernel<<<B * CG * NSC, 256, 0, stream>>>(feats, aux, stats, out);
}

// Round 6
// 406.762 us; speedup vs baseline: 1.3470x; 1.3470x over previous
//
#include <hip/hip_runtime.h>
#include <math.h>

#define B 8
#define C 512
#define K 19
#define HW 16384
#define ROWS (B * K)             // 152
#define L2E 1.44269504088896340736f

// softmax two-phase config
#define NSEG 8
#define SEG (HW / NSEG)          // 2048 elements per segment

// gather config
#define NW 4                     // waves per block
#define CPW 4                    // c-rows per wave -> acc[4][19] = 76 VGPRs
#define CPB (CPW * NW)           // 16 c-rows per block
#define CG (C / CPB)             // 32 c-groups
#define NSC 4                    // grid = 8*32*4 = 1024 = 4 blocks/CU
#define SCHUNK (HW / NSC)        // 4096 s per block
#define TS 256                   // s-tile staged in LDS
#define NT (SCHUNK / TS)         // 16 tiles per block

// Phase A: per-(row,segment) partial softmax stats.
__global__ __launch_bounds__(256)
void softmax_partial_kernel(const float* __restrict__ aux, float* __restrict__ partials) {
    int blk = blockIdx.x;                  // 0 .. ROWS*NSEG-1
    int row = blk >> 3;
    int seg = blk & (NSEG - 1);
    const float4* x4 = (const float4*)(aux + (size_t)row * HW + seg * SEG);
    int tid  = threadIdx.x;
    int lane = tid & 63;
    int wave = tid >> 6;
    __shared__ float red[4];

    float4 v0 = x4[tid];
    float4 v1 = x4[tid + 256];
    float m = fmaxf(fmaxf(fmaxf(v0.x, v0.y), fmaxf(v0.z, v0.w)),
                    fmaxf(fmaxf(v1.x, v1.y), fmaxf(v1.z, v1.w)));
    #pragma unroll
    for (int off = 32; off > 0; off >>= 1) m = fmaxf(m, __shfl_xor(m, off, 64));
    if (lane == 0) red[wave] = m;
    __syncthreads();
    m = fmaxf(fmaxf(red[0], red[1]), fmaxf(red[2], red[3]));
    __syncthreads();

    float s = exp2f((v0.x - m) * L2E) + exp2f((v0.y - m) * L2E)
            + exp2f((v0.z - m) * L2E) + exp2f((v0.w - m) * L2E)
            + exp2f((v1.x - m) * L2E) + exp2f((v1.y - m) * L2E)
            + exp2f((v1.z - m) * L2E) + exp2f((v1.w - m) * L2E);
    #pragma unroll
    for (int off = 32; off > 0; off >>= 1) s += __shfl_xor(s, off, 64);
    if (lane == 0) red[wave] = s;
    __syncthreads();
    if (tid == 0) {
        partials[blk * 2]     = m;
        partials[blk * 2 + 1] = red[0] + red[1] + red[2] + red[3];
    }
}

// Phase B: combine NSEG partials per row (online-softmax merge).
__global__ __launch_bounds__(256)
void softmax_combine_kernel(const float* __restrict__ partials, float* __restrict__ stats) {
    int row = threadIdx.x;
    if (row < ROWS) {
        float mj[NSEG], zj[NSEG];
        float m = -INFINITY;
        #pragma unroll
        for (int j = 0; j < NSEG; j++) {
            mj[j] = partials[(row * NSEG + j) * 2];
            zj[j] = partials[(row * NSEG + j) * 2 + 1];
            m = fmaxf(m, mj[j]);
        }
        float Z = 0.f;
        #pragma unroll
        for (int j = 0; j < NSEG; j++) Z += zj[j] * exp2f((mj[j] - m) * L2E);
        stats[row * 2]     = -m * L2E;
        stats[row * 2 + 1] = 1.0f / Z;
    }
}

// Gather. ALLOCATOR LAW (R1-R5 measured): VGPR budget = 512/(2*declared_min_waves_per_eu).
// waves_per_eu(2) -> budget 128 (R1/R3 confirmed: chooses 128, no spill at ~125 live).
// Declaring 4 (launch_bounds 2nd arg or waves_per_eu) -> 64 VGPRs -> catastrophic spill
// (R2/R4/R5: WRITE_SIZE 237MB-2.9GB). Do NOT "fix" this to match actual occupancy.
// Occupancy comes from LDS: 38,912 B -> 4 blocks/CU = 16 waves/CU.
__global__ __launch_bounds__(256)
__attribute__((amdgpu_waves_per_eu(2)))
void gather_kernel(const float* __restrict__ feats, const float* __restrict__ aux,
                   const float* __restrict__ stats, float* __restrict__ out) {
    __shared__ float plds[2][K][TS];          // 38,912 B -> 4 blocks/CU

    int bid  = blockIdx.x;                 // 0 .. 1023
    int sc   = bid & (NSC - 1);
    int cg   = (bid >> 2) & (CG - 1);
    int b    = bid >> 7;
    int tid  = threadIdx.x;
    int lane = tid & 63;
    int wave = tid >> 6;
    int c0   = cg * CPB + wave * CPW;

    const float* Abase = aux   + (size_t)b * K * HW + sc * SCHUNK;
    const float* Fbase = feats + ((size_t)b * C + c0) * HW + sc * SCHUNK;
    const float* S     = stats + (size_t)b * K * 2;

    // softmax stats -> SGPRs
    float negml[K], invz[K];
    #pragma unroll
    for (int k = 0; k < K; k++) {
        negml[k] = __int_as_float(__builtin_amdgcn_readfirstlane(__float_as_int(S[2 * k])));
        invz[k]  = __int_as_float(__builtin_amdgcn_readfirstlane(__float_as_int(S[2 * k + 1])));
    }

    float acc[CPW][K];
    #pragma unroll
    for (int c = 0; c < CPW; c++)
        #pragma unroll
        for (int k = 0; k < K; k++) acc[c][k] = 0.f;

    // prologue: stage probs tile 0 + load feats tile 0
    #pragma unroll
    for (int k = 0; k < K; k++) {
        float a = Abase[k * HW + tid];
        plds[0][k][tid] = exp2f(fmaf(a, L2E, negml[k])) * invz[k];
    }
    float4 f_cur[CPW], f_next[CPW];
    #pragma unroll
    for (int c = 0; c < CPW; c++)
        f_cur[c] = *(const float4*)(Fbase + c * HW + lane * 4);

    for (int t = 0; t < NT; t++) {
        int buf = t & 1;
        __syncthreads();   // plds[buf] staged; prior readers of buf^1 done

        // prefetch feats t+1 first (longest latency distance), then stage
        // probs t+1 into the other LDS buffer (aux windowed in groups of 5
        // to bound live registers under the 128 budget).
        if (t + 1 < NT) {
            int s1 = (t + 1) * TS;
            #pragma unroll
            for (int c = 0; c < CPW; c++)
                f_next[c] = *(const float4*)(Fbase + c * HW + s1 + lane * 4);
            #pragma unroll
            for (int kb = 0; kb < K; kb += 5) {
                float a[5];
                const int ke = (kb + 5 < K) ? kb + 5 : K;
                #pragma unroll
                for (int k = kb; k < ke; k++) a[k - kb] = Abase[k * HW + s1 + tid];
                #pragma unroll
                for (int k = kb; k < ke; k++)
                    plds[buf ^ 1][k][tid] = exp2f(fmaf(a[k - kb], L2E, negml[k])) * invz[k];
            }
        }

        // FMA phase on tile t: f_cur (regs) x plds[buf] (ds_read_b128)
        #pragma unroll
        for (int k = 0; k < K; k++) {
            float4 p4 = *(const float4*)(&plds[buf][k][lane * 4]);
            #pragma unroll
            for (int c = 0; c < CPW; c++) {
                acc[c][k] = fmaf(p4.x, f_cur[c].x, acc[c][k]);
                acc[c][k] = fmaf(p4.y, f_cur[c].y, acc[c][k]);
                acc[c][k] = fmaf(p4.z, f_cur[c].z, acc[c][k]);
                acc[c][k] = fmaf(p4.w, f_cur[c].w, acc[c][k]);
            }
        }
        #pragma unroll
        for (int c = 0; c < CPW; c++) f_cur[c] = f_next[c];
    }

    // butterfly reduce over 64 lanes, then one atomic per (c,k) per block
    #pragma unroll
    for (int c = 0; c < CPW; c++)
        #pragma unroll
        for (int k = 0; k < K; k++) {
            float v = acc[c][k];
            #pragma unroll
            for (int off = 32; off > 0; off >>= 1) v += __shfl_xor(v, off, 64);
            if (lane == 0)
                atomicAdd(&out[((size_t)b * C + c0 + c) * K + k], v);
        }
}

extern "C" void kernel_launch(void* const* d_in, const int* in_sizes, int n_in,
                              void* d_out, int out_size, void* d_ws, size_t ws_size,
                              hipStream_t stream) {
    const float* feats = (const float*)d_in[0];   // bb_feats [8,512,128,128]
    const float* aux   = (const float*)d_in[1];   // aux_out  [8,19,128,128]
    float* out      = (float*)d_out;              // [8,512,19,1]
    float* stats    = (float*)d_ws;               // 304 floats
    float* partials = (float*)d_ws + 512;         // 152*8*2 floats

    hipMemsetAsync(d_out, 0, (size_t)out_size * sizeof(float), stream);
    softmax_partial_kernel<<<ROWS * NSEG, 256, 0, stream>>>(aux, partials);
    softmax_combine_kernel<<<1, 256, 0, stream>>>(partials, stats);
    gather_kernel<<<B * CG * NSC, 256, 0, stream>>>(feats, aux, stats, out);
}